// Round 1
// baseline (1457.093 us; speedup 1.0000x reference)
//
#include <hip/hip_runtime.h>

// GCN layer: out = A_sparse @ (X @ W) + bias
// X: [50000,128] f32, edge_index: [2,800000] i32 (row=dst, col=src),
// edge_weight: [800000] f32, W: [128,128] f32, bias: [128] f32.
// Plan: K1 gemm S=X@W -> d_ws (25.6MB), K2 out=bias, K3 edge scatter-atomics.

#define N_NODES 50000
#define N_EDGES 800000
#define D 128

// ---------------- K1: S = X @ W ----------------
// block 256 threads, 32 rows/block. W (64KB) + X tile (16KB) in LDS.
// thread t: col-quad cq = t&31 (4 cols), row-group rg = t>>5 (4 rows) ->
// 4x4 acc micro-tile. Per k4 step: 4 ds_read_b128 (W) + 4 ds_read_b128 (X)
// feed 64 FMAs.
__global__ __launch_bounds__(256) void gemm_kernel(const float* __restrict__ X,
                                                   const float* __restrict__ W,
                                                   float* __restrict__ S) {
    __shared__ float wlds[D * D];      // 64 KB
    __shared__ float xlds[32 * D];     // 16 KB
    const int t = threadIdx.x;
    const int row0 = blockIdx.x * 32;

    // stage W: 4096 float4, 16 per thread, coalesced
    const float4* W4 = (const float4*)W;
    float4* wl4 = (float4*)wlds;
#pragma unroll
    for (int i = 0; i < 16; ++i) wl4[t + 256 * i] = W4[t + 256 * i];

    // stage X tile: 1024 float4, 4 per thread, coalesced
    const float4* X4 = (const float4*)X;
    float4* xl4 = (float4*)xlds;
#pragma unroll
    for (int i = 0; i < 4; ++i) {
        int idx = t + 256 * i;            // 0..1023, local row = idx>>5
        if (row0 + (idx >> 5) < N_NODES) xl4[idx] = X4[row0 * 32 + idx];
    }
    __syncthreads();

    const int cq = t & 31;   // column quad: cols cq*4 .. cq*4+3
    const int rg = t >> 5;   // row group: local rows rg*4 .. rg*4+3

    float4 acc[4];
#pragma unroll
    for (int r = 0; r < 4; ++r) acc[r] = make_float4(0.f, 0.f, 0.f, 0.f);

#pragma unroll 4
    for (int k4 = 0; k4 < 32; ++k4) {
        const int kb = k4 * 4;
        float4 w0 = wl4[(kb + 0) * 32 + cq];
        float4 w1 = wl4[(kb + 1) * 32 + cq];
        float4 w2 = wl4[(kb + 2) * 32 + cq];
        float4 w3 = wl4[(kb + 3) * 32 + cq];
#pragma unroll
        for (int r = 0; r < 4; ++r) {
            float4 x = xl4[(rg * 4 + r) * 32 + k4];   // LDS broadcast per half-wave
            acc[r].x += x.x * w0.x + x.y * w1.x + x.z * w2.x + x.w * w3.x;
            acc[r].y += x.x * w0.y + x.y * w1.y + x.z * w2.y + x.w * w3.y;
            acc[r].z += x.x * w0.z + x.y * w1.z + x.z * w2.z + x.w * w3.z;
            acc[r].w += x.x * w0.w + x.y * w1.w + x.z * w2.w + x.w * w3.w;
        }
    }

    float4* S4 = (float4*)S;
#pragma unroll
    for (int r = 0; r < 4; ++r) {
        int gr = row0 + rg * 4 + r;
        if (gr < N_NODES) S4[gr * 32 + cq] = acc[r];
    }
}

// ---------------- K2: out[n][d] = bias[d] ----------------
__global__ __launch_bounds__(256) void init_kernel(float* __restrict__ out,
                                                   const float* __restrict__ bias) {
    int i = blockIdx.x * 256 + threadIdx.x;     // over N_NODES*32 float4
    if (i < N_NODES * 32) ((float4*)out)[i] = ((const float4*)bias)[i & 31];
}

// ---------------- K3: out[row[e]] += S[col[e]] * w[e] ----------------
// 32 threads per edge; each thread: one float4 gather + 4 f32 atomics.
__global__ __launch_bounds__(256) void scatter_kernel(const float* __restrict__ S,
                                                      const int* __restrict__ ei,
                                                      const float* __restrict__ ew,
                                                      float* __restrict__ out) {
    int gid = blockIdx.x * 256 + threadIdx.x;
    int e = gid >> 5;
    if (e >= N_EDGES) return;
    int q = gid & 31;
    int row = ei[e];             // dst
    int col = ei[N_EDGES + e];   // src
    float w = ew[e];
    float4 s = ((const float4*)S)[col * 32 + q];
    float* dst = out + row * D + q * 4;
    atomicAdd(dst + 0, s.x * w);
    atomicAdd(dst + 1, s.y * w);
    atomicAdd(dst + 2, s.z * w);
    atomicAdd(dst + 3, s.w * w);
}

extern "C" void kernel_launch(void* const* d_in, const int* in_sizes, int n_in,
                              void* d_out, int out_size, void* d_ws, size_t ws_size,
                              hipStream_t stream) {
    const float* X    = (const float*)d_in[0];
    const int*   ei   = (const int*)d_in[1];
    const float* ew   = (const float*)d_in[2];
    const float* W    = (const float*)d_in[3];
    const float* bias = (const float*)d_in[4];
    float* out = (float*)d_out;
    float* S   = (float*)d_ws;   // 50000*128*4 = 25.6 MB scratch

    gemm_kernel<<<(N_NODES + 31) / 32, 256, 0, stream>>>(X, W, S);
    init_kernel<<<(N_NODES * 32 + 255) / 256, 256, 0, stream>>>(out, bias);
    scatter_kernel<<<(N_EDGES * 32 + 255) / 256, 256, 0, stream>>>(S, ei, ew, out);
}

// Round 2
// 269.144 us; speedup vs baseline: 5.4138x; 5.4138x over previous
//
#include <hip/hip_runtime.h>

// GCN layer: out = A_sparse @ (X @ W) + bias
// R2: replace output-atomic scatter (1340us, L2-thrashing HBM RMW atomics)
// with device-side counting-sort by dst row + per-node segment reduction.

#define N_NODES 50000
#define N_EDGES 800000
#define D 128
#define SCAN_BLOCKS 196            // ceil(50000/256)
#define N_PAD (SCAN_BLOCKS * 256)  // 50176

// ---- ws layout (bytes) ----
// S:        [0, 25600000)               50000*128*4
// count:    [25600000, +200704)         50176 ints
// start:    [25800704, +200704)
// cursor:   [26001408, +200704)
// blocksum: [26202112, +1024)           256 ints
// blockoff: [26203136, +1024)
// packed:   [26204160, +6400000)        800000 int2 (col, bits(w))

// ---------------- K1: S = X @ W (f32, LDS-tiled) ----------------
__global__ __launch_bounds__(256) void gemm_kernel(const float* __restrict__ X,
                                                   const float* __restrict__ W,
                                                   float* __restrict__ S) {
    __shared__ float wlds[D * D];
    __shared__ float xlds[32 * D];
    const int t = threadIdx.x;
    const int row0 = blockIdx.x * 32;

    const float4* W4 = (const float4*)W;
    float4* wl4 = (float4*)wlds;
#pragma unroll
    for (int i = 0; i < 16; ++i) wl4[t + 256 * i] = W4[t + 256 * i];

    const float4* X4 = (const float4*)X;
    float4* xl4 = (float4*)xlds;
#pragma unroll
    for (int i = 0; i < 4; ++i) {
        int idx = t + 256 * i;
        if (row0 + (idx >> 5) < N_NODES) xl4[idx] = X4[row0 * 32 + idx];
    }
    __syncthreads();

    const int cq = t & 31;
    const int rg = t >> 5;

    float4 acc[4];
#pragma unroll
    for (int r = 0; r < 4; ++r) acc[r] = make_float4(0.f, 0.f, 0.f, 0.f);

#pragma unroll 4
    for (int k4 = 0; k4 < 32; ++k4) {
        const int kb = k4 * 4;
        float4 w0 = wl4[(kb + 0) * 32 + cq];
        float4 w1 = wl4[(kb + 1) * 32 + cq];
        float4 w2 = wl4[(kb + 2) * 32 + cq];
        float4 w3 = wl4[(kb + 3) * 32 + cq];
#pragma unroll
        for (int r = 0; r < 4; ++r) {
            float4 x = xl4[(rg * 4 + r) * 32 + k4];
            acc[r].x += x.x * w0.x + x.y * w1.x + x.z * w2.x + x.w * w3.x;
            acc[r].y += x.x * w0.y + x.y * w1.y + x.z * w2.y + x.w * w3.y;
            acc[r].z += x.x * w0.z + x.y * w1.z + x.z * w2.z + x.w * w3.z;
            acc[r].w += x.x * w0.w + x.y * w1.w + x.z * w2.w + x.w * w3.w;
        }
    }

    float4* S4 = (float4*)S;
#pragma unroll
    for (int r = 0; r < 4; ++r) {
        int gr = row0 + rg * 4 + r;
        if (gr < N_NODES) S4[gr * 32 + cq] = acc[r];
    }
}

// ---------------- K2: zero the histogram ----------------
__global__ __launch_bounds__(256) void zero_kernel(int* __restrict__ count) {
    int i = blockIdx.x * 256 + threadIdx.x;
    if (i < N_PAD) count[i] = 0;
}

// ---------------- K3: histogram of dst rows ----------------
__global__ __launch_bounds__(256) void hist_kernel(const int* __restrict__ ei,
                                                   int* __restrict__ count) {
    int e = blockIdx.x * 256 + threadIdx.x;
    if (e < N_EDGES) atomicAdd(&count[ei[e]], 1);
}

// ---------------- K4a: per-block exclusive scan + block sums ----------------
__global__ __launch_bounds__(256) void scan1_kernel(const int* __restrict__ count,
                                                    int* __restrict__ start,
                                                    int* __restrict__ blocksum) {
    __shared__ int wsum[4];
    int t = threadIdx.x;
    int i = blockIdx.x * 256 + t;
    int lane = t & 63, wid = t >> 6;
    int v = (i < N_NODES) ? count[i] : 0;
    int incl = v;
#pragma unroll
    for (int off = 1; off < 64; off <<= 1) {
        int x = __shfl_up(incl, off, 64);
        if (lane >= off) incl += x;
    }
    if (lane == 63) wsum[wid] = incl;
    __syncthreads();
    if (t == 0) {
        int a = 0;
#pragma unroll
        for (int w = 0; w < 4; ++w) { int x = wsum[w]; wsum[w] = a; a += x; }
        blocksum[blockIdx.x] = a;
    }
    __syncthreads();
    start[i] = incl - v + wsum[wid];   // local-exclusive; i < N_PAD always
}

// ---------------- K4b: scan the 196 block sums ----------------
__global__ __launch_bounds__(256) void scan2_kernel(const int* __restrict__ blocksum,
                                                    int* __restrict__ blockoff) {
    __shared__ int wsum[4];
    int t = threadIdx.x;
    int lane = t & 63, wid = t >> 6;
    int v = (t < SCAN_BLOCKS) ? blocksum[t] : 0;
    int incl = v;
#pragma unroll
    for (int off = 1; off < 64; off <<= 1) {
        int x = __shfl_up(incl, off, 64);
        if (lane >= off) incl += x;
    }
    if (lane == 63) wsum[wid] = incl;
    __syncthreads();
    if (t == 0) {
        int a = 0;
#pragma unroll
        for (int w = 0; w < 4; ++w) { int x = wsum[w]; wsum[w] = a; a += x; }
    }
    __syncthreads();
    blockoff[t] = incl - v + wsum[wid];
}

// ---------------- K4c: add block offsets; init cursors ----------------
__global__ __launch_bounds__(256) void scan3_kernel(int* __restrict__ start,
                                                    const int* __restrict__ blockoff,
                                                    int* __restrict__ cursor) {
    int i = blockIdx.x * 256 + threadIdx.x;
    int s = start[i] + blockoff[i >> 8];
    start[i] = s;
    cursor[i] = s;
}

// ---------------- K5: bin edges by dst row ----------------
__global__ __launch_bounds__(256) void binscatter_kernel(const int* __restrict__ ei,
                                                         const float* __restrict__ ew,
                                                         int* __restrict__ cursor,
                                                         int2* __restrict__ packed) {
    int e = blockIdx.x * 256 + threadIdx.x;
    if (e >= N_EDGES) return;
    int row = ei[e];
    int col = ei[N_EDGES + e];
    float w = ew[e];
    int p = atomicAdd(&cursor[row], 1);
    packed[p] = make_int2(col, __float_as_int(w));
}

// ---------------- K6: per-node segment sum (no atomics) ----------------
// 32 lanes per node, each lane owns one float4 (4 of 128 dims).
__global__ __launch_bounds__(256) void gather_kernel(const float* __restrict__ S,
                                                     const int* __restrict__ start,
                                                     const int* __restrict__ count,
                                                     const int2* __restrict__ packed,
                                                     const float* __restrict__ bias,
                                                     float* __restrict__ out) {
    int g = blockIdx.x * 8 + (threadIdx.x >> 5);   // node
    if (g >= N_NODES) return;
    int q = threadIdx.x & 31;
    int beg = start[g];
    int end = beg + count[g];
    const float4* S4 = (const float4*)S;
    float4 acc = make_float4(0.f, 0.f, 0.f, 0.f);
    for (int p = beg; p < end; ++p) {
        int2 cw = packed[p];                       // broadcast across 32 lanes
        float w = __int_as_float(cw.y);
        float4 s = S4[cw.x * 32 + q];              // 512B contiguous per group
        acc.x += s.x * w;
        acc.y += s.y * w;
        acc.z += s.z * w;
        acc.w += s.w * w;
    }
    float4 b = ((const float4*)bias)[q];
    acc.x += b.x; acc.y += b.y; acc.z += b.z; acc.w += b.w;
    ((float4*)out)[g * 32 + q] = acc;
}

extern "C" void kernel_launch(void* const* d_in, const int* in_sizes, int n_in,
                              void* d_out, int out_size, void* d_ws, size_t ws_size,
                              hipStream_t stream) {
    const float* X    = (const float*)d_in[0];
    const int*   ei   = (const int*)d_in[1];
    const float* ew   = (const float*)d_in[2];
    const float* W    = (const float*)d_in[3];
    const float* bias = (const float*)d_in[4];
    float* out = (float*)d_out;

    char* ws = (char*)d_ws;
    float* S        = (float*)(ws);
    int*   count    = (int*)(ws + 25600000);
    int*   start    = (int*)(ws + 25800704);
    int*   cursor   = (int*)(ws + 26001408);
    int*   blocksum = (int*)(ws + 26202112);
    int*   blockoff = (int*)(ws + 26203136);
    int2*  packed   = (int2*)(ws + 26204160);

    gemm_kernel<<<(N_NODES + 31) / 32, 256, 0, stream>>>(X, W, S);
    zero_kernel<<<SCAN_BLOCKS, 256, 0, stream>>>(count);
    hist_kernel<<<(N_EDGES + 255) / 256, 256, 0, stream>>>(ei, count);
    scan1_kernel<<<SCAN_BLOCKS, 256, 0, stream>>>(count, start, blocksum);
    scan2_kernel<<<1, 256, 0, stream>>>(blocksum, blockoff);
    scan3_kernel<<<SCAN_BLOCKS, 256, 0, stream>>>(start, blockoff, cursor);
    binscatter_kernel<<<(N_EDGES + 255) / 256, 256, 0, stream>>>(ei, ew, cursor, packed);
    gather_kernel<<<(N_NODES + 7) / 8, 256, 0, stream>>>(S, start, count, packed, bias, out);
}

// Round 3
// 241.277 us; speedup vs baseline: 6.0391x; 1.1155x over previous
//
#include <hip/hip_runtime.h>

// GCN layer: out = A_sparse @ (X @ W) + bias
// R3: S kept in bf16 (halves gather fetch traffic) + MFMA bf16 GEMM.
// Sort pipeline (hist/scan/binscatter) unchanged from R2.

#define N_NODES 50000
#define N_EDGES 800000
#define D 128
#define SCAN_BLOCKS 196            // ceil(50000/256)
#define N_PAD (SCAN_BLOCKS * 256)  // 50176

typedef short bf16x8 __attribute__((ext_vector_type(8)));
typedef float f32x4 __attribute__((ext_vector_type(4)));

__device__ inline unsigned short f2bf(float f) {   // RNE f32 -> bf16 bits
    unsigned u = __float_as_uint(f);
    unsigned r = (u + 0x7FFFu + ((u >> 16) & 1u)) >> 16;
    return (unsigned short)r;
}

// ---- ws layout (bytes) ----
// S16:      [0, 12800000)            50000*128*2 bf16
// count:    [12800000, +200704)
// start:    [13000704, +200704)
// cursor:   [13201408, +200704)
// blocksum: [13402112, +1024)
// blockoff: [13403136, +1024)
// packed:   [13404160, +6400000)     800000 int2 (col, bits(w))

// ---------------- K1: S16 = bf16(X @ W), MFMA ----------------
// 64 rows x 128 cols per block, 256 threads = 4 waves, wave w -> rows w*16..+15.
// LDS: wt = W^T bf16 [128][136] (pad 8 keeps 16B align: 136*2=272=17*16B),
//      xt = X tile bf16 [64][136], reused as output staging.
__global__ __launch_bounds__(256) void gemm_kernel(const float* __restrict__ X,
                                                   const float* __restrict__ W,
                                                   unsigned short* __restrict__ S16) {
    __shared__ unsigned short wt[128 * 136];
    __shared__ unsigned short xt[64 * 136];
    const int t = threadIdx.x;
    const int row0 = blockIdx.x * 64;

    // stage W^T bf16: scalar coalesced reads, scattered b16 LDS writes
#pragma unroll
    for (int i = 0; i < 64; ++i) {
        int idx = t + 256 * i;            // flat over [k][n]
        float w = W[idx];
        int k = idx >> 7, n = idx & 127;
        wt[n * 136 + k] = f2bf(w);
    }

    // stage X tile bf16: float4 coalesced reads, packed 8B LDS writes
    const float4* X4 = (const float4*)X;
#pragma unroll
    for (int i = 0; i < 8; ++i) {
        int idx4 = t + 256 * i;           // 0..2047: r = idx4>>5, c4 = idx4&31
        int r = idx4 >> 5, c4 = idx4 & 31;
        int gr = row0 + r;
        float4 v = make_float4(0.f, 0.f, 0.f, 0.f);
        if (gr < N_NODES) v = X4[gr * 32 + c4];
        ushort4 u = make_ushort4(f2bf(v.x), f2bf(v.y), f2bf(v.z), f2bf(v.w));
        *(ushort4*)&xt[r * 136 + c4 * 4] = u;
    }
    __syncthreads();

    const int wv = t >> 6;
    const int lane = t & 63;
    const int m = lane & 15;      // A row / B col within 16
    const int q = lane >> 4;      // k-quad: k = q*8 + j
    const int rbase = wv * 16;

    f32x4 acc[8];
#pragma unroll
    for (int nt = 0; nt < 8; ++nt) acc[nt] = (f32x4){0.f, 0.f, 0.f, 0.f};

#pragma unroll
    for (int ks = 0; ks < 4; ++ks) {
        bf16x8 a = *(const bf16x8*)&xt[(rbase + m) * 136 + ks * 32 + q * 8];
#pragma unroll
        for (int nt = 0; nt < 8; ++nt) {
            bf16x8 b = *(const bf16x8*)&wt[(nt * 16 + m) * 136 + ks * 32 + q * 8];
            acc[nt] = __builtin_amdgcn_mfma_f32_16x16x32_bf16(a, b, acc[nt], 0, 0, 0);
        }
    }

    // epilogue: C/D layout col=lane&15, row=(lane>>4)*4+reg -> stage in xt, then coalesced
    __syncthreads();
#pragma unroll
    for (int nt = 0; nt < 8; ++nt) {
        int col = nt * 16 + m;
#pragma unroll
        for (int r = 0; r < 4; ++r) {
            int rl = rbase + q * 4 + r;
            xt[rl * 136 + col] = f2bf(acc[nt][r]);
        }
    }
    __syncthreads();
#pragma unroll
    for (int i = 0; i < 4; ++i) {
        int id = t + 256 * i;             // 1024 chunks of 8 bf16
        int r = id >> 4, c8 = (id & 15) * 8;
        int gr = row0 + r;
        if (gr < N_NODES)
            *(uint4*)&S16[gr * 128 + c8] = *(const uint4*)&xt[r * 136 + c8];
    }
}

// ---------------- K2: zero the histogram ----------------
__global__ __launch_bounds__(256) void zero_kernel(int* __restrict__ count) {
    int i = blockIdx.x * 256 + threadIdx.x;
    if (i < N_PAD) count[i] = 0;
}

// ---------------- K3: histogram of dst rows ----------------
__global__ __launch_bounds__(256) void hist_kernel(const int* __restrict__ ei,
                                                   int* __restrict__ count) {
    int e = blockIdx.x * 256 + threadIdx.x;
    if (e < N_EDGES) atomicAdd(&count[ei[e]], 1);
}

// ---------------- K4a: per-block exclusive scan + block sums ----------------
__global__ __launch_bounds__(256) void scan1_kernel(const int* __restrict__ count,
                                                    int* __restrict__ start,
                                                    int* __restrict__ blocksum) {
    __shared__ int wsum[4];
    int t = threadIdx.x;
    int i = blockIdx.x * 256 + t;
    int lane = t & 63, wid = t >> 6;
    int v = (i < N_NODES) ? count[i] : 0;
    int incl = v;
#pragma unroll
    for (int off = 1; off < 64; off <<= 1) {
        int x = __shfl_up(incl, off, 64);
        if (lane >= off) incl += x;
    }
    if (lane == 63) wsum[wid] = incl;
    __syncthreads();
    if (t == 0) {
        int a = 0;
#pragma unroll
        for (int w = 0; w < 4; ++w) { int x = wsum[w]; wsum[w] = a; a += x; }
        blocksum[blockIdx.x] = a;
    }
    __syncthreads();
    start[i] = incl - v + wsum[wid];
}

// ---------------- K4b: scan the block sums ----------------
__global__ __launch_bounds__(256) void scan2_kernel(const int* __restrict__ blocksum,
                                                    int* __restrict__ blockoff) {
    __shared__ int wsum[4];
    int t = threadIdx.x;
    int lane = t & 63, wid = t >> 6;
    int v = (t < SCAN_BLOCKS) ? blocksum[t] : 0;
    int incl = v;
#pragma unroll
    for (int off = 1; off < 64; off <<= 1) {
        int x = __shfl_up(incl, off, 64);
        if (lane >= off) incl += x;
    }
    if (lane == 63) wsum[wid] = incl;
    __syncthreads();
    if (t == 0) {
        int a = 0;
#pragma unroll
        for (int w = 0; w < 4; ++w) { int x = wsum[w]; wsum[w] = a; a += x; }
    }
    __syncthreads();
    blockoff[t] = incl - v + wsum[wid];
}

// ---------------- K4c: add block offsets; init cursors ----------------
__global__ __launch_bounds__(256) void scan3_kernel(int* __restrict__ start,
                                                    const int* __restrict__ blockoff,
                                                    int* __restrict__ cursor) {
    int i = blockIdx.x * 256 + threadIdx.x;
    int s = start[i] + blockoff[i >> 8];
    start[i] = s;
    cursor[i] = s;
}

// ---------------- K5: bin edges by dst row ----------------
__global__ __launch_bounds__(256) void binscatter_kernel(const int* __restrict__ ei,
                                                         const float* __restrict__ ew,
                                                         int* __restrict__ cursor,
                                                         int2* __restrict__ packed) {
    int e = blockIdx.x * 256 + threadIdx.x;
    if (e >= N_EDGES) return;
    int row = ei[e];
    int col = ei[N_EDGES + e];
    float w = ew[e];
    int p = atomicAdd(&cursor[row], 1);
    packed[p] = make_int2(col, __float_as_int(w));
}

// ---------------- K6: per-node segment sum over bf16 S ----------------
// 32 lanes per node; lane q owns dims q*4..q*4+3 (8B bf16x4 load, f32 acc).
__global__ __launch_bounds__(256) void gather_kernel(const unsigned short* __restrict__ S16,
                                                     const int* __restrict__ start,
                                                     const int* __restrict__ count,
                                                     const int2* __restrict__ packed,
                                                     const float* __restrict__ bias,
                                                     float* __restrict__ out) {
    int g = blockIdx.x * 8 + (threadIdx.x >> 5);
    if (g >= N_NODES) return;
    int q = threadIdx.x & 31;
    int beg = start[g];
    int end = beg + count[g];
    const uint2* S2 = (const uint2*)S16;   // 4 bf16 per 8B
    float4 acc = make_float4(0.f, 0.f, 0.f, 0.f);
    for (int p = beg; p < end; ++p) {
        int2 cw = packed[p];               // broadcast across the 32-lane group
        float w = __int_as_float(cw.y);
        uint2 v = S2[cw.x * 32 + q];       // 256B contiguous per edge row
        float f0 = __uint_as_float(v.x << 16);
        float f1 = __uint_as_float(v.x & 0xFFFF0000u);
        float f2 = __uint_as_float(v.y << 16);
        float f3 = __uint_as_float(v.y & 0xFFFF0000u);
        acc.x += f0 * w;
        acc.y += f1 * w;
        acc.z += f2 * w;
        acc.w += f3 * w;
    }
    float4 b = ((const float4*)bias)[q];
    acc.x += b.x; acc.y += b.y; acc.z += b.z; acc.w += b.w;
    ((float4*)out)[g * 32 + q] = acc;
}

extern "C" void kernel_launch(void* const* d_in, const int* in_sizes, int n_in,
                              void* d_out, int out_size, void* d_ws, size_t ws_size,
                              hipStream_t stream) {
    const float* X    = (const float*)d_in[0];
    const int*   ei   = (const int*)d_in[1];
    const float* ew   = (const float*)d_in[2];
    const float* W    = (const float*)d_in[3];
    const float* bias = (const float*)d_in[4];
    float* out = (float*)d_out;

    char* ws = (char*)d_ws;
    unsigned short* S16 = (unsigned short*)(ws);
    int*   count    = (int*)(ws + 12800000);
    int*   start    = (int*)(ws + 13000704);
    int*   cursor   = (int*)(ws + 13201408);
    int*   blocksum = (int*)(ws + 13402112);
    int*   blockoff = (int*)(ws + 13403136);
    int2*  packed   = (int2*)(ws + 13404160);

    gemm_kernel<<<(N_NODES + 63) / 64, 256, 0, stream>>>(X, W, S16);
    zero_kernel<<<SCAN_BLOCKS, 256, 0, stream>>>(count);
    hist_kernel<<<(N_EDGES + 255) / 256, 256, 0, stream>>>(ei, count);
    scan1_kernel<<<SCAN_BLOCKS, 256, 0, stream>>>(count, start, blocksum);
    scan2_kernel<<<1, 256, 0, stream>>>(blocksum, blockoff);
    scan3_kernel<<<SCAN_BLOCKS, 256, 0, stream>>>(start, blockoff, cursor);
    binscatter_kernel<<<(N_EDGES + 255) / 256, 256, 0, stream>>>(ei, ew, cursor, packed);
    gather_kernel<<<(N_NODES + 7) / 8, 256, 0, stream>>>(S16, start, count, packed, bias, out);
}

// Round 4
// 226.863 us; speedup vs baseline: 6.4228x; 1.0635x over previous
//
#include <hip/hip_runtime.h>

// GCN layer: out = A_sparse @ (X @ W) + bias
// R4: attack the two latency-bound kernels with MLP:
//  - gather: wave-per-node, 4 edges in flight (16 lanes x 16B per edge row),
//    shfl_xor cross-subgroup reduce.
//  - binscatter/hist: 4 edges per thread (independent atomics/writes).

#define N_NODES 50000
#define N_EDGES 800000
#define D 128
#define SCAN_BLOCKS 196            // ceil(50000/256)
#define N_PAD (SCAN_BLOCKS * 256)  // 50176

typedef short bf16x8 __attribute__((ext_vector_type(8)));
typedef float f32x4 __attribute__((ext_vector_type(4)));

__device__ inline unsigned short f2bf(float f) {   // RNE f32 -> bf16 bits
    unsigned u = __float_as_uint(f);
    unsigned r = (u + 0x7FFFu + ((u >> 16) & 1u)) >> 16;
    return (unsigned short)r;
}

// ---- ws layout (bytes) ----
// S16:      [0, 12800000)            50000*128*2 bf16
// count:    [12800000, +200704)
// start:    [13000704, +200704)
// cursor:   [13201408, +200704)
// blocksum: [13402112, +1024)
// blockoff: [13403136, +1024)
// packed:   [13404160, +6400000)     800000 int2 (col, bits(w))

// ---------------- K1: S16 = bf16(X @ W), MFMA ----------------
__global__ __launch_bounds__(256) void gemm_kernel(const float* __restrict__ X,
                                                   const float* __restrict__ W,
                                                   unsigned short* __restrict__ S16) {
    __shared__ unsigned short wt[128 * 136];
    __shared__ unsigned short xt[64 * 136];
    const int t = threadIdx.x;
    const int row0 = blockIdx.x * 64;

#pragma unroll
    for (int i = 0; i < 64; ++i) {
        int idx = t + 256 * i;            // flat over [k][n]
        float w = W[idx];
        int k = idx >> 7, n = idx & 127;
        wt[n * 136 + k] = f2bf(w);
    }

    const float4* X4 = (const float4*)X;
#pragma unroll
    for (int i = 0; i < 8; ++i) {
        int idx4 = t + 256 * i;
        int r = idx4 >> 5, c4 = idx4 & 31;
        int gr = row0 + r;
        float4 v = make_float4(0.f, 0.f, 0.f, 0.f);
        if (gr < N_NODES) v = X4[gr * 32 + c4];
        ushort4 u = make_ushort4(f2bf(v.x), f2bf(v.y), f2bf(v.z), f2bf(v.w));
        *(ushort4*)&xt[r * 136 + c4 * 4] = u;
    }
    __syncthreads();

    const int wv = t >> 6;
    const int lane = t & 63;
    const int m = lane & 15;
    const int q = lane >> 4;
    const int rbase = wv * 16;

    f32x4 acc[8];
#pragma unroll
    for (int nt = 0; nt < 8; ++nt) acc[nt] = (f32x4){0.f, 0.f, 0.f, 0.f};

#pragma unroll
    for (int ks = 0; ks < 4; ++ks) {
        bf16x8 a = *(const bf16x8*)&xt[(rbase + m) * 136 + ks * 32 + q * 8];
#pragma unroll
        for (int nt = 0; nt < 8; ++nt) {
            bf16x8 b = *(const bf16x8*)&wt[(nt * 16 + m) * 136 + ks * 32 + q * 8];
            acc[nt] = __builtin_amdgcn_mfma_f32_16x16x32_bf16(a, b, acc[nt], 0, 0, 0);
        }
    }

    __syncthreads();
#pragma unroll
    for (int nt = 0; nt < 8; ++nt) {
        int col = nt * 16 + m;
#pragma unroll
        for (int r = 0; r < 4; ++r) {
            int rl = rbase + q * 4 + r;
            xt[rl * 136 + col] = f2bf(acc[nt][r]);
        }
    }
    __syncthreads();
#pragma unroll
    for (int i = 0; i < 4; ++i) {
        int id = t + 256 * i;
        int r = id >> 4, c8 = (id & 15) * 8;
        int gr = row0 + r;
        if (gr < N_NODES)
            *(uint4*)&S16[gr * 128 + c8] = *(const uint4*)&xt[r * 136 + c8];
    }
}

// ---------------- K2: zero the histogram ----------------
__global__ __launch_bounds__(256) void zero_kernel(int* __restrict__ count) {
    int i = blockIdx.x * 256 + threadIdx.x;
    if (i < N_PAD) count[i] = 0;
}

// ---------------- K3: histogram of dst rows, 4 edges/thread ----------------
#define QT ((N_EDGES + 3) / 4)   // 200000 threads
__global__ __launch_bounds__(256) void hist_kernel(const int* __restrict__ ei,
                                                   int* __restrict__ count) {
    int tid = blockIdx.x * 256 + threadIdx.x;
    if (tid >= QT) return;
    int r0 = ei[tid];
    int r1 = ei[tid + QT];
    int r2 = ei[tid + 2 * QT];
    int r3 = (tid + 3 * QT < N_EDGES) ? ei[tid + 3 * QT] : -1;
    atomicAdd(&count[r0], 1);
    atomicAdd(&count[r1], 1);
    atomicAdd(&count[r2], 1);
    if (r3 >= 0) atomicAdd(&count[r3], 1);
}

// ---------------- K4a: per-block exclusive scan + block sums ----------------
__global__ __launch_bounds__(256) void scan1_kernel(const int* __restrict__ count,
                                                    int* __restrict__ start,
                                                    int* __restrict__ blocksum) {
    __shared__ int wsum[4];
    int t = threadIdx.x;
    int i = blockIdx.x * 256 + t;
    int lane = t & 63, wid = t >> 6;
    int v = (i < N_NODES) ? count[i] : 0;
    int incl = v;
#pragma unroll
    for (int off = 1; off < 64; off <<= 1) {
        int x = __shfl_up(incl, off, 64);
        if (lane >= off) incl += x;
    }
    if (lane == 63) wsum[wid] = incl;
    __syncthreads();
    if (t == 0) {
        int a = 0;
#pragma unroll
        for (int w = 0; w < 4; ++w) { int x = wsum[w]; wsum[w] = a; a += x; }
        blocksum[blockIdx.x] = a;
    }
    __syncthreads();
    start[i] = incl - v + wsum[wid];
}

// ---------------- K4b: scan the block sums ----------------
__global__ __launch_bounds__(256) void scan2_kernel(const int* __restrict__ blocksum,
                                                    int* __restrict__ blockoff) {
    __shared__ int wsum[4];
    int t = threadIdx.x;
    int lane = t & 63, wid = t >> 6;
    int v = (t < SCAN_BLOCKS) ? blocksum[t] : 0;
    int incl = v;
#pragma unroll
    for (int off = 1; off < 64; off <<= 1) {
        int x = __shfl_up(incl, off, 64);
        if (lane >= off) incl += x;
    }
    if (lane == 63) wsum[wid] = incl;
    __syncthreads();
    if (t == 0) {
        int a = 0;
#pragma unroll
        for (int w = 0; w < 4; ++w) { int x = wsum[w]; wsum[w] = a; a += x; }
    }
    __syncthreads();
    blockoff[t] = incl - v + wsum[wid];
}

// ---------------- K4c: add block offsets; init cursors ----------------
__global__ __launch_bounds__(256) void scan3_kernel(int* __restrict__ start,
                                                    const int* __restrict__ blockoff,
                                                    int* __restrict__ cursor) {
    int i = blockIdx.x * 256 + threadIdx.x;
    int s = start[i] + blockoff[i >> 8];
    start[i] = s;
    cursor[i] = s;
}

// ---------------- K5: bin edges by dst row, 4 edges/thread ----------------
__global__ __launch_bounds__(256) void binscatter_kernel(const int* __restrict__ ei,
                                                         const float* __restrict__ ew,
                                                         int* __restrict__ cursor,
                                                         int2* __restrict__ packed) {
    int tid = blockIdx.x * 256 + threadIdx.x;
    if (tid >= QT) return;
    int e0 = tid, e1 = tid + QT, e2 = tid + 2 * QT, e3 = tid + 3 * QT;
    int r0 = ei[e0], r1 = ei[e1], r2 = ei[e2];
    int c0 = ei[N_EDGES + e0], c1 = ei[N_EDGES + e1], c2 = ei[N_EDGES + e2];
    float w0 = ew[e0], w1 = ew[e1], w2 = ew[e2];
    int p0 = atomicAdd(&cursor[r0], 1);
    int p1 = atomicAdd(&cursor[r1], 1);
    int p2 = atomicAdd(&cursor[r2], 1);
    packed[p0] = make_int2(c0, __float_as_int(w0));
    packed[p1] = make_int2(c1, __float_as_int(w1));
    packed[p2] = make_int2(c2, __float_as_int(w2));
    if (e3 < N_EDGES) {
        int r3 = ei[e3], c3 = ei[N_EDGES + e3];
        float w3 = ew[e3];
        int p3 = atomicAdd(&cursor[r3], 1);
        packed[p3] = make_int2(c3, __float_as_int(w3));
    }
}

// ---------------- K6: segment sum, wave-per-node, 4 edges in flight ----------
// 64 lanes per node: sub = lane>>4 picks edge p, p+1, p+2, p+3; q = lane&15
// owns dims q*8..q*8+7 (one uint4 = 8 bf16 per edge). Final shfl_xor reduce.
__global__ __launch_bounds__(256) void gather_kernel(const unsigned short* __restrict__ S16,
                                                     const int* __restrict__ start,
                                                     const int* __restrict__ count,
                                                     const int2* __restrict__ packed,
                                                     const float* __restrict__ bias,
                                                     float* __restrict__ out) {
    int g = blockIdx.x * 4 + (threadIdx.x >> 6);
    if (g >= N_NODES) return;
    int lane = threadIdx.x & 63;
    int sub = lane >> 4;
    int q = lane & 15;
    int beg = start[g];
    int end = beg + count[g];
    const uint4* S4 = (const uint4*)S16;     // row stride: 16 uint4
    float acc[8] = {0.f, 0.f, 0.f, 0.f, 0.f, 0.f, 0.f, 0.f};
    for (int p = beg + sub; p < end; p += 4) {
        int2 cw = packed[p];
        float w = __int_as_float(cw.y);
        uint4 v = S4[cw.x * 16 + q];         // 16 lanes x 16B = 256B row
        acc[0] += __uint_as_float(v.x << 16) * w;
        acc[1] += __uint_as_float(v.x & 0xFFFF0000u) * w;
        acc[2] += __uint_as_float(v.y << 16) * w;
        acc[3] += __uint_as_float(v.y & 0xFFFF0000u) * w;
        acc[4] += __uint_as_float(v.z << 16) * w;
        acc[5] += __uint_as_float(v.z & 0xFFFF0000u) * w;
        acc[6] += __uint_as_float(v.w << 16) * w;
        acc[7] += __uint_as_float(v.w & 0xFFFF0000u) * w;
    }
#pragma unroll
    for (int i = 0; i < 8; ++i) acc[i] += __shfl_xor(acc[i], 16, 64);
#pragma unroll
    for (int i = 0; i < 8; ++i) acc[i] += __shfl_xor(acc[i], 32, 64);
    if (sub == 0) {
        float4 b0 = ((const float4*)bias)[q * 2];
        float4 b1 = ((const float4*)bias)[q * 2 + 1];
        float4 o0 = make_float4(acc[0] + b0.x, acc[1] + b0.y, acc[2] + b0.z, acc[3] + b0.w);
        float4 o1 = make_float4(acc[4] + b1.x, acc[5] + b1.y, acc[6] + b1.z, acc[7] + b1.w);
        ((float4*)out)[g * 32 + q * 2] = o0;
        ((float4*)out)[g * 32 + q * 2 + 1] = o1;
    }
}

extern "C" void kernel_launch(void* const* d_in, const int* in_sizes, int n_in,
                              void* d_out, int out_size, void* d_ws, size_t ws_size,
                              hipStream_t stream) {
    const float* X    = (const float*)d_in[0];
    const int*   ei   = (const int*)d_in[1];
    const float* ew   = (const float*)d_in[2];
    const float* W    = (const float*)d_in[3];
    const float* bias = (const float*)d_in[4];
    float* out = (float*)d_out;

    char* ws = (char*)d_ws;
    unsigned short* S16 = (unsigned short*)(ws);
    int*   count    = (int*)(ws + 12800000);
    int*   start    = (int*)(ws + 13000704);
    int*   cursor   = (int*)(ws + 13201408);
    int*   blocksum = (int*)(ws + 13402112);
    int*   blockoff = (int*)(ws + 13403136);
    int2*  packed   = (int2*)(ws + 13404160);

    gemm_kernel<<<(N_NODES + 63) / 64, 256, 0, stream>>>(X, W, S16);
    zero_kernel<<<SCAN_BLOCKS, 256, 0, stream>>>(count);
    hist_kernel<<<(QT + 255) / 256, 256, 0, stream>>>(ei, count);
    scan1_kernel<<<SCAN_BLOCKS, 256, 0, stream>>>(count, start, blocksum);
    scan2_kernel<<<1, 256, 0, stream>>>(blocksum, blockoff);
    scan3_kernel<<<SCAN_BLOCKS, 256, 0, stream>>>(start, blockoff, cursor);
    binscatter_kernel<<<(QT + 255) / 256, 256, 0, stream>>>(ei, ew, cursor, packed);
    gather_kernel<<<(N_NODES + 3) / 4, 256, 0, stream>>>(S16, start, count, packed, bias, out);
}

// Round 5
// 162.279 us; speedup vs baseline: 8.9789x; 1.3980x over previous
//
#include <hip/hip_runtime.h>

// GCN layer: out = A_sparse @ (X @ W) + bias
// R5: replace hist/scan/binscatter (random 8B writes -> 52MB WRITE_SIZE, 64B
// line amplification) with a two-level LDS-staged counting sort:
//  pass1: bucket multisplit (bucket=row>>8, 196 buckets), LDS reorder ->
//         coalesced writes into fixed per-bucket slots.
//  pass2: per-bucket LDS sort by row + CSR start/count emission, in-place.

#define N_NODES 50000
#define N_EDGES 800000
#define D 128
#define N_PAD 50176            // 196*256
#define NBUCKET 196            // rows 0..50175 in buckets of 256 (row>>8)
#define SLOT 6144              // per-bucket slot capacity (mean 4082, +32 sigma)
#define CHUNK 2048             // edges per pass1 block
#define EPT 8                  // CHUNK/256

typedef short bf16x8 __attribute__((ext_vector_type(8)));
typedef float f32x4 __attribute__((ext_vector_type(4)));

__device__ inline unsigned short f2bf(float f) {   // RNE f32 -> bf16 bits
    unsigned u = __float_as_uint(f);
    unsigned r = (u + 0x7FFFu + ((u >> 16) & 1u)) >> 16;
    return (unsigned short)r;
}

// ---- ws layout (bytes) ----
// S16:      [0, 12800000)            50000*128*2 bf16
// staging:  [12800000, 22433792)     196*6144 int2 (row<<16|col, bits(w))
// start:    [22433792, +200704)      50176 ints
// count:    [22634496, +200704)
// gcursor:  [22835200, +1024)        196 bucket cursors

// ---------------- K1: S16 = bf16(X @ W), MFMA ----------------
__global__ __launch_bounds__(256) void gemm_kernel(const float* __restrict__ X,
                                                   const float* __restrict__ W,
                                                   unsigned short* __restrict__ S16) {
    __shared__ unsigned short wt[128 * 136];
    __shared__ unsigned short xt[64 * 136];
    const int t = threadIdx.x;
    const int row0 = blockIdx.x * 64;

#pragma unroll
    for (int i = 0; i < 64; ++i) {
        int idx = t + 256 * i;            // flat over [k][n]
        float w = W[idx];
        int k = idx >> 7, n = idx & 127;
        wt[n * 136 + k] = f2bf(w);
    }

    const float4* X4 = (const float4*)X;
#pragma unroll
    for (int i = 0; i < 8; ++i) {
        int idx4 = t + 256 * i;
        int r = idx4 >> 5, c4 = idx4 & 31;
        int gr = row0 + r;
        float4 v = make_float4(0.f, 0.f, 0.f, 0.f);
        if (gr < N_NODES) v = X4[gr * 32 + c4];
        ushort4 u = make_ushort4(f2bf(v.x), f2bf(v.y), f2bf(v.z), f2bf(v.w));
        *(ushort4*)&xt[r * 136 + c4 * 4] = u;
    }
    __syncthreads();

    const int wv = t >> 6;
    const int lane = t & 63;
    const int m = lane & 15;
    const int q = lane >> 4;
    const int rbase = wv * 16;

    f32x4 acc[8];
#pragma unroll
    for (int nt = 0; nt < 8; ++nt) acc[nt] = (f32x4){0.f, 0.f, 0.f, 0.f};

#pragma unroll
    for (int ks = 0; ks < 4; ++ks) {
        bf16x8 a = *(const bf16x8*)&xt[(rbase + m) * 136 + ks * 32 + q * 8];
#pragma unroll
        for (int nt = 0; nt < 8; ++nt) {
            bf16x8 b = *(const bf16x8*)&wt[(nt * 16 + m) * 136 + ks * 32 + q * 8];
            acc[nt] = __builtin_amdgcn_mfma_f32_16x16x32_bf16(a, b, acc[nt], 0, 0, 0);
        }
    }

    __syncthreads();
#pragma unroll
    for (int nt = 0; nt < 8; ++nt) {
        int col = nt * 16 + m;
#pragma unroll
        for (int r = 0; r < 4; ++r) {
            int rl = rbase + q * 4 + r;
            xt[rl * 136 + col] = f2bf(acc[nt][r]);
        }
    }
    __syncthreads();
#pragma unroll
    for (int i = 0; i < 4; ++i) {
        int id = t + 256 * i;
        int r = id >> 4, c8 = (id & 15) * 8;
        int gr = row0 + r;
        if (gr < N_NODES)
            *(uint4*)&S16[gr * 128 + c8] = *(const uint4*)&xt[r * 136 + c8];
    }
}

// ---------------- K2: zero bucket cursors ----------------
__global__ __launch_bounds__(256) void zero_kernel(int* __restrict__ gcursor) {
    int t = threadIdx.x;
    if (t < NBUCKET) gcursor[t] = 0;
}

// ---------------- K3: pass1 bucket multisplit ----------------
__global__ __launch_bounds__(256) void pass1_kernel(const int* __restrict__ ei,
                                                    const float* __restrict__ ew,
                                                    int* __restrict__ gcursor,
                                                    int2* __restrict__ staging) {
    __shared__ int hist[256];
    __shared__ int s[256];
    __shared__ int lcur[256];
    __shared__ int bmg[256];
    __shared__ int2 buf[CHUNK];
    __shared__ unsigned char bof[CHUNK];
    const int t = threadIdx.x;
    const int base = blockIdx.x * CHUNK;

    hist[t] = 0;
    __syncthreads();

    int rows[EPT];
#pragma unroll
    for (int i = 0; i < EPT; ++i) {
        int e = base + t + 256 * i;
        rows[i] = (e < N_EDGES) ? ei[e] : -1;
        if (rows[i] >= 0) atomicAdd(&hist[rows[i] >> 8], 1);
    }
    __syncthreads();

    // inclusive Hillis-Steele scan of hist into s
    s[t] = hist[t];
    __syncthreads();
    for (int off = 1; off < 256; off <<= 1) {
        int u = (t >= off) ? s[t - off] : 0;
        __syncthreads();
        s[t] += u;
        __syncthreads();
    }
    int ex = s[t] - hist[t];          // exclusive scan
    lcur[t] = ex;
    int gb = 0;
    if (t < NBUCKET && hist[t] > 0) gb = atomicAdd(&gcursor[t], hist[t]);
    bmg[t] = t * SLOT + gb - ex;      // gaddr = bmg[b] + local_sorted_pos
    __syncthreads();

    // local reorder into bucket-contiguous LDS buffer
#pragma unroll
    for (int i = 0; i < EPT; ++i) {
        if (rows[i] >= 0) {
            int e = base + t + 256 * i;
            int col = ei[N_EDGES + e];
            float w = ew[e];
            int b = rows[i] >> 8;
            int lp = atomicAdd(&lcur[b], 1);
            buf[lp] = make_int2((int)(((unsigned)rows[i] << 16) | (unsigned)col),
                                __float_as_int(w));
            bof[lp] = (unsigned char)b;
        }
    }
    __syncthreads();

    // coalesced sweep: consecutive lp in same bucket -> consecutive gaddr
    int total = s[255];
    for (int lp = t; lp < total; lp += 256) {
        int b = bof[lp];
        int g = bmg[b] + lp;
        if (g < (b + 1) * SLOT) staging[g] = buf[lp];   // overflow guard (unreachable)
    }
}

// ---------------- K4: pass2 per-bucket sort by row + CSR ----------------
__global__ __launch_bounds__(256) void pass2_kernel(const int* __restrict__ gcursor,
                                                    int2* __restrict__ staging,
                                                    int* __restrict__ start,
                                                    int* __restrict__ count) {
    __shared__ int hist[256];
    __shared__ int s[256];
    __shared__ int lcur[256];
    __shared__ int2 in0[SLOT];   // 48 KB
    __shared__ int2 in1[SLOT];   // 48 KB
    const int t = threadIdx.x;
    const int b = blockIdx.x;
    int cnt = gcursor[b];
    if (cnt > SLOT) cnt = SLOT;

    hist[t] = 0;
    __syncthreads();
    for (int i = t; i < cnt; i += 256) {
        int2 v = staging[b * SLOT + i];
        in0[i] = v;
        int lr = (int)(((unsigned)v.x) >> 24 ? 0 : 0);   // placeholder (see below)
        lr = (int)((((unsigned)v.x) >> 16) & 255u);
        atomicAdd(&hist[lr], 1);
    }
    __syncthreads();

    s[t] = hist[t];
    __syncthreads();
    for (int off = 1; off < 256; off <<= 1) {
        int u = (t >= off) ? s[t - off] : 0;
        __syncthreads();
        s[t] += u;
        __syncthreads();
    }
    int ex = s[t] - hist[t];
    lcur[t] = ex;
    int g = b * 256 + t;              // row id, < N_PAD
    start[g] = b * SLOT + ex;
    count[g] = hist[t];
    __syncthreads();

    for (int i = t; i < cnt; i += 256) {
        int2 v = in0[i];
        int lr = (int)((((unsigned)v.x) >> 16) & 255u);
        int p = atomicAdd(&lcur[lr], 1);
        in1[p] = v;
    }
    __syncthreads();
    for (int i = t; i < cnt; i += 256)
        staging[b * SLOT + i] = in1[i];
}

// ---------------- K5: segment sum, wave-per-node, 4 edges in flight ----------
__global__ __launch_bounds__(256) void gather_kernel(const unsigned short* __restrict__ S16,
                                                     const int* __restrict__ start,
                                                     const int* __restrict__ count,
                                                     const int2* __restrict__ packed,
                                                     const float* __restrict__ bias,
                                                     float* __restrict__ out) {
    int g = blockIdx.x * 4 + (threadIdx.x >> 6);
    if (g >= N_NODES) return;
    int lane = threadIdx.x & 63;
    int sub = lane >> 4;
    int q = lane & 15;
    int beg = start[g];
    int end = beg + count[g];
    const uint4* S4 = (const uint4*)S16;
    float acc[8] = {0.f, 0.f, 0.f, 0.f, 0.f, 0.f, 0.f, 0.f};
    for (int p = beg + sub; p < end; p += 4) {
        int2 cw = packed[p];
        float w = __int_as_float(cw.y);
        int col = cw.x & 0xFFFF;
        uint4 v = S4[col * 16 + q];
        acc[0] += __uint_as_float(v.x << 16) * w;
        acc[1] += __uint_as_float(v.x & 0xFFFF0000u) * w;
        acc[2] += __uint_as_float(v.y << 16) * w;
        acc[3] += __uint_as_float(v.y & 0xFFFF0000u) * w;
        acc[4] += __uint_as_float(v.z << 16) * w;
        acc[5] += __uint_as_float(v.z & 0xFFFF0000u) * w;
        acc[6] += __uint_as_float(v.w << 16) * w;
        acc[7] += __uint_as_float(v.w & 0xFFFF0000u) * w;
    }
#pragma unroll
    for (int i = 0; i < 8; ++i) acc[i] += __shfl_xor(acc[i], 16, 64);
#pragma unroll
    for (int i = 0; i < 8; ++i) acc[i] += __shfl_xor(acc[i], 32, 64);
    if (sub == 0) {
        float4 b0 = ((const float4*)bias)[q * 2];
        float4 b1 = ((const float4*)bias)[q * 2 + 1];
        float4 o0 = make_float4(acc[0] + b0.x, acc[1] + b0.y, acc[2] + b0.z, acc[3] + b0.w);
        float4 o1 = make_float4(acc[4] + b1.x, acc[5] + b1.y, acc[6] + b1.z, acc[7] + b1.w);
        ((float4*)out)[g * 32 + q * 2] = o0;
        ((float4*)out)[g * 32 + q * 2 + 1] = o1;
    }
}

extern "C" void kernel_launch(void* const* d_in, const int* in_sizes, int n_in,
                              void* d_out, int out_size, void* d_ws, size_t ws_size,
                              hipStream_t stream) {
    const float* X    = (const float*)d_in[0];
    const int*   ei   = (const int*)d_in[1];
    const float* ew   = (const float*)d_in[2];
    const float* W    = (const float*)d_in[3];
    const float* bias = (const float*)d_in[4];
    float* out = (float*)d_out;

    char* ws = (char*)d_ws;
    unsigned short* S16 = (unsigned short*)(ws);
    int2* staging = (int2*)(ws + 12800000);
    int*  start   = (int*)(ws + 22433792);
    int*  count   = (int*)(ws + 22634496);
    int*  gcursor = (int*)(ws + 22835200);

    gemm_kernel<<<(N_NODES + 63) / 64, 256, 0, stream>>>(X, W, S16);
    zero_kernel<<<1, 256, 0, stream>>>(gcursor);
    pass1_kernel<<<(N_EDGES + CHUNK - 1) / CHUNK, 256, 0, stream>>>(ei, ew, gcursor, staging);
    pass2_kernel<<<NBUCKET, 256, 0, stream>>>(gcursor, staging, start, count);
    gather_kernel<<<(N_NODES + 3) / 4, 256, 0, stream>>>(S16, start, count, staging, bias, out);
}

// Round 6
// 153.834 us; speedup vs baseline: 9.4719x; 1.0549x over previous
//
#include <hip/hip_runtime.h>

// GCN layer: out = A_sparse @ (X @ W) + bias
// R6: gather 8 edges in flight (sub=lane>>3, 2xuint4 per lane); wave-shfl
// scans in pass1/pass2 (2 syncs instead of 16); zero fused into gemm.

#define N_NODES 50000
#define N_EDGES 800000
#define D 128
#define N_PAD 50176            // 196*256
#define NBUCKET 196            // rows 0..50175 in buckets of 256 (row>>8)
#define SLOT 6144              // per-bucket slot capacity (mean 4096, +32 sigma)
#define CHUNK 2048             // edges per pass1 block
#define EPT 8                  // CHUNK/256

typedef short bf16x8 __attribute__((ext_vector_type(8)));
typedef float f32x4 __attribute__((ext_vector_type(4)));

__device__ inline unsigned short f2bf(float f) {   // RNE f32 -> bf16 bits
    unsigned u = __float_as_uint(f);
    unsigned r = (u + 0x7FFFu + ((u >> 16) & 1u)) >> 16;
    return (unsigned short)r;
}

// ---- ws layout (bytes) ----
// S16:      [0, 12800000)            50000*128*2 bf16
// staging:  [12800000, 22433792)     196*6144 int2 (row<<16|col, bits(w))
// start:    [22433792, +200704)      50176 ints
// count:    [22634496, +200704)
// gcursor:  [22835200, +1024)        196 bucket cursors

// ---------------- K1: S16 = bf16(X @ W), MFMA; also zeros gcursor ----------
__global__ __launch_bounds__(256) void gemm_kernel(const float* __restrict__ X,
                                                   const float* __restrict__ W,
                                                   unsigned short* __restrict__ S16,
                                                   int* __restrict__ gcursor) {
    __shared__ unsigned short wt[128 * 136];
    __shared__ unsigned short xt[64 * 136];
    const int t = threadIdx.x;
    const int row0 = blockIdx.x * 64;

    if (blockIdx.x == 0 && t < NBUCKET) gcursor[t] = 0;

#pragma unroll
    for (int i = 0; i < 64; ++i) {
        int idx = t + 256 * i;            // flat over [k][n]
        float w = W[idx];
        int k = idx >> 7, n = idx & 127;
        wt[n * 136 + k] = f2bf(w);
    }

    const float4* X4 = (const float4*)X;
#pragma unroll
    for (int i = 0; i < 8; ++i) {
        int idx4 = t + 256 * i;
        int r = idx4 >> 5, c4 = idx4 & 31;
        int gr = row0 + r;
        float4 v = make_float4(0.f, 0.f, 0.f, 0.f);
        if (gr < N_NODES) v = X4[gr * 32 + c4];
        ushort4 u = make_ushort4(f2bf(v.x), f2bf(v.y), f2bf(v.z), f2bf(v.w));
        *(ushort4*)&xt[r * 136 + c4 * 4] = u;
    }
    __syncthreads();

    const int wv = t >> 6;
    const int lane = t & 63;
    const int m = lane & 15;
    const int q = lane >> 4;
    const int rbase = wv * 16;

    f32x4 acc[8];
#pragma unroll
    for (int nt = 0; nt < 8; ++nt) acc[nt] = (f32x4){0.f, 0.f, 0.f, 0.f};

#pragma unroll
    for (int ks = 0; ks < 4; ++ks) {
        bf16x8 a = *(const bf16x8*)&xt[(rbase + m) * 136 + ks * 32 + q * 8];
#pragma unroll
        for (int nt = 0; nt < 8; ++nt) {
            bf16x8 b = *(const bf16x8*)&wt[(nt * 16 + m) * 136 + ks * 32 + q * 8];
            acc[nt] = __builtin_amdgcn_mfma_f32_16x16x32_bf16(a, b, acc[nt], 0, 0, 0);
        }
    }

    __syncthreads();
#pragma unroll
    for (int nt = 0; nt < 8; ++nt) {
        int col = nt * 16 + m;
#pragma unroll
        for (int r = 0; r < 4; ++r) {
            int rl = rbase + q * 4 + r;
            xt[rl * 136 + col] = f2bf(acc[nt][r]);
        }
    }
    __syncthreads();
#pragma unroll
    for (int i = 0; i < 4; ++i) {
        int id = t + 256 * i;
        int r = id >> 4, c8 = (id & 15) * 8;
        int gr = row0 + r;
        if (gr < N_NODES)
            *(uint4*)&S16[gr * 128 + c8] = *(const uint4*)&xt[r * 136 + c8];
    }
}

// ---------------- K2: pass1 bucket multisplit ----------------
__global__ __launch_bounds__(256) void pass1_kernel(const int* __restrict__ ei,
                                                    const float* __restrict__ ew,
                                                    int* __restrict__ gcursor,
                                                    int2* __restrict__ staging) {
    __shared__ int hist[256];
    __shared__ int lcur[256];
    __shared__ int bmg[256];
    __shared__ int wsum[4];
    __shared__ int2 buf[CHUNK];
    __shared__ unsigned char bof[CHUNK];
    const int t = threadIdx.x;
    const int base = blockIdx.x * CHUNK;
    const int lane = t & 63, wid = t >> 6;

    hist[t] = 0;
    __syncthreads();

    int rows[EPT];
#pragma unroll
    for (int i = 0; i < EPT; ++i) {
        int e = base + t + 256 * i;
        rows[i] = (e < N_EDGES) ? ei[e] : -1;
        if (rows[i] >= 0) atomicAdd(&hist[rows[i] >> 8], 1);
    }
    __syncthreads();

    // wave-shfl exclusive scan of hist[256]
    int v = hist[t];
    int incl = v;
#pragma unroll
    for (int off = 1; off < 64; off <<= 1) {
        int x = __shfl_up(incl, off, 64);
        if (lane >= off) incl += x;
    }
    if (lane == 63) wsum[wid] = incl;
    __syncthreads();
    int pre = 0, total = 0;
#pragma unroll
    for (int w = 0; w < 4; ++w) {
        int x = wsum[w];
        if (w < wid) pre += x;
        total += x;
    }
    int ex = incl - v + pre;
    lcur[t] = ex;
    int gb = 0;
    if (t < NBUCKET && v > 0) gb = atomicAdd(&gcursor[t], v);
    bmg[t] = t * SLOT + gb - ex;      // gaddr = bmg[b] + local_sorted_pos
    __syncthreads();

    // local reorder into bucket-contiguous LDS buffer
#pragma unroll
    for (int i = 0; i < EPT; ++i) {
        if (rows[i] >= 0) {
            int e = base + t + 256 * i;
            int col = ei[N_EDGES + e];
            float w = ew[e];
            int b = rows[i] >> 8;
            int lp = atomicAdd(&lcur[b], 1);
            buf[lp] = make_int2((int)(((unsigned)rows[i] << 16) | (unsigned)col),
                                __float_as_int(w));
            bof[lp] = (unsigned char)b;
        }
    }
    __syncthreads();

    // coalesced sweep: consecutive lp in same bucket -> consecutive gaddr
    for (int lp = t; lp < total; lp += 256) {
        int b = bof[lp];
        int g = bmg[b] + lp;
        if (g < (b + 1) * SLOT) staging[g] = buf[lp];   // overflow guard
    }
}

// ---------------- K3: pass2 per-bucket sort by row + CSR ----------------
__global__ __launch_bounds__(256) void pass2_kernel(const int* __restrict__ gcursor,
                                                    int2* __restrict__ staging,
                                                    int* __restrict__ start,
                                                    int* __restrict__ count) {
    __shared__ int hist[256];
    __shared__ int lcur[256];
    __shared__ int wsum[4];
    __shared__ int2 in0[SLOT];   // 48 KB
    __shared__ int2 in1[SLOT];   // 48 KB
    const int t = threadIdx.x;
    const int b = blockIdx.x;
    const int lane = t & 63, wid = t >> 6;
    int cnt = gcursor[b];
    if (cnt > SLOT) cnt = SLOT;

    hist[t] = 0;
    __syncthreads();
    for (int i = t; i < cnt; i += 256) {
        int2 v2 = staging[b * SLOT + i];
        in0[i] = v2;
        int lr = (int)((((unsigned)v2.x) >> 16) & 255u);
        atomicAdd(&hist[lr], 1);
    }
    __syncthreads();

    int v = hist[t];
    int incl = v;
#pragma unroll
    for (int off = 1; off < 64; off <<= 1) {
        int x = __shfl_up(incl, off, 64);
        if (lane >= off) incl += x;
    }
    if (lane == 63) wsum[wid] = incl;
    __syncthreads();
    int pre = 0;
#pragma unroll
    for (int w = 0; w < 4; ++w) if (w < wid) pre += wsum[w];
    int ex = incl - v + pre;
    lcur[t] = ex;
    int g = b * 256 + t;              // row id, < N_PAD
    start[g] = b * SLOT + ex;
    count[g] = v;
    __syncthreads();

    for (int i = t; i < cnt; i += 256) {
        int2 e = in0[i];
        int lr = (int)((((unsigned)e.x) >> 16) & 255u);
        int p = atomicAdd(&lcur[lr], 1);
        in1[p] = e;
    }
    __syncthreads();
    for (int i = t; i < cnt; i += 256)
        staging[b * SLOT + i] = in1[i];
}

// ---------------- K4: segment sum, wave-per-node, 8 edges in flight ----------
// sub = lane>>3 picks edges p, p+1, ..., p+7; q = lane&7 owns dims
// q*16..q*16+15 (two uint4 = 16 bf16). 3-round shfl_xor reduce over subs.
__global__ __launch_bounds__(256) void gather_kernel(const unsigned short* __restrict__ S16,
                                                     const int* __restrict__ start,
                                                     const int* __restrict__ count,
                                                     const int2* __restrict__ packed,
                                                     const float* __restrict__ bias,
                                                     float* __restrict__ out) {
    int g = blockIdx.x * 4 + (threadIdx.x >> 6);
    if (g >= N_NODES) return;
    int lane = threadIdx.x & 63;
    int sub = lane >> 3;
    int q = lane & 7;
    int beg = start[g];
    int end = beg + count[g];
    const uint4* S4 = (const uint4*)S16;     // row stride: 16 uint4
    float acc[16];
#pragma unroll
    for (int i = 0; i < 16; ++i) acc[i] = 0.f;
    for (int p = beg + sub; p < end; p += 8) {
        int2 cw = packed[p];
        float w = __int_as_float(cw.y);
        int col = cw.x & 0xFFFF;
        uint4 v0 = S4[col * 16 + q * 2];
        uint4 v1 = S4[col * 16 + q * 2 + 1];
        acc[0]  += __uint_as_float(v0.x << 16) * w;
        acc[1]  += __uint_as_float(v0.x & 0xFFFF0000u) * w;
        acc[2]  += __uint_as_float(v0.y << 16) * w;
        acc[3]  += __uint_as_float(v0.y & 0xFFFF0000u) * w;
        acc[4]  += __uint_as_float(v0.z << 16) * w;
        acc[5]  += __uint_as_float(v0.z & 0xFFFF0000u) * w;
        acc[6]  += __uint_as_float(v0.w << 16) * w;
        acc[7]  += __uint_as_float(v0.w & 0xFFFF0000u) * w;
        acc[8]  += __uint_as_float(v1.x << 16) * w;
        acc[9]  += __uint_as_float(v1.x & 0xFFFF0000u) * w;
        acc[10] += __uint_as_float(v1.y << 16) * w;
        acc[11] += __uint_as_float(v1.y & 0xFFFF0000u) * w;
        acc[12] += __uint_as_float(v1.z << 16) * w;
        acc[13] += __uint_as_float(v1.z & 0xFFFF0000u) * w;
        acc[14] += __uint_as_float(v1.w << 16) * w;
        acc[15] += __uint_as_float(v1.w & 0xFFFF0000u) * w;
    }
#pragma unroll
    for (int i = 0; i < 16; ++i) acc[i] += __shfl_xor(acc[i], 8, 64);
#pragma unroll
    for (int i = 0; i < 16; ++i) acc[i] += __shfl_xor(acc[i], 16, 64);
#pragma unroll
    for (int i = 0; i < 16; ++i) acc[i] += __shfl_xor(acc[i], 32, 64);
    if (sub == 0) {
        const float4* bias4 = (const float4*)bias;
#pragma unroll
        for (int j = 0; j < 4; ++j) {
            float4 bb = bias4[q * 4 + j];
            float4 o = make_float4(acc[4 * j + 0] + bb.x, acc[4 * j + 1] + bb.y,
                                   acc[4 * j + 2] + bb.z, acc[4 * j + 3] + bb.w);
            ((float4*)out)[g * 32 + q * 4 + j] = o;
        }
    }
}

extern "C" void kernel_launch(void* const* d_in, const int* in_sizes, int n_in,
                              void* d_out, int out_size, void* d_ws, size_t ws_size,
                              hipStream_t stream) {
    const float* X    = (const float*)d_in[0];
    const int*   ei   = (const int*)d_in[1];
    const float* ew   = (const float*)d_in[2];
    const float* W    = (const float*)d_in[3];
    const float* bias = (const float*)d_in[4];
    float* out = (float*)d_out;

    char* ws = (char*)d_ws;
    unsigned short* S16 = (unsigned short*)(ws);
    int2* staging = (int2*)(ws + 12800000);
    int*  start   = (int*)(ws + 22433792);
    int*  count   = (int*)(ws + 22634496);
    int*  gcursor = (int*)(ws + 22835200);

    gemm_kernel<<<(N_NODES + 63) / 64, 256, 0, stream>>>(X, W, S16, gcursor);
    pass1_kernel<<<(N_EDGES + CHUNK - 1) / CHUNK, 256, 0, stream>>>(ei, ew, gcursor, staging);
    pass2_kernel<<<NBUCKET, 256, 0, stream>>>(gcursor, staging, start, count);
    gather_kernel<<<(N_NODES + 3) / 4, 256, 0, stream>>>(S16, start, count, staging, bias, out);
}